// Round 1
// baseline (628.215 us; speedup 1.0000x reference)
//
#include <hip/hip_runtime.h>
#include <hip/hip_bf16.h>
#include <cstdint>

#define N_NODES 50000
#define N_EDGES 800000
#define BATCH   1024
#define GENE    256
#define HID     128
#define FEAT    64

// ---------------- degree / CSR build ----------------

__global__ void k_deg(const int* __restrict__ dst, int* __restrict__ deg) {
  int e = blockIdx.x * blockDim.x + threadIdx.x;
  if (e < N_EDGES) atomicAdd(&deg[dst[e]], 1);
}

__global__ void k_scan1(const int* __restrict__ deg, int* __restrict__ bsum) {
  __shared__ int s[512];
  int t = threadIdx.x;
  int i = blockIdx.x * 512 + t;
  s[t] = (i < N_NODES) ? deg[i] : 0;
  __syncthreads();
  for (int off = 256; off > 0; off >>= 1) {
    if (t < off) s[t] += s[t + off];
    __syncthreads();
  }
  if (t == 0) bsum[blockIdx.x] = s[0];
}

__global__ void k_scan2(int* bsum, int nb) {
  if (threadIdx.x == 0 && blockIdx.x == 0) {
    int acc = 0;
    for (int b = 0; b < nb; ++b) { int v = bsum[b]; bsum[b] = acc; acc += v; }
  }
}

__global__ void k_scan3(const int* __restrict__ deg, const int* __restrict__ bsum,
                        int* __restrict__ row_ptr) {
  __shared__ int s[512];
  int t = threadIdx.x;
  int i = blockIdx.x * 512 + t;
  int v = (i < N_NODES) ? deg[i] : 0;
  s[t] = v;
  __syncthreads();
  for (int off = 1; off < 512; off <<= 1) {
    int add = (t >= off) ? s[t - off] : 0;
    __syncthreads();
    s[t] += add;
    __syncthreads();
  }
  int incl = s[t] + bsum[blockIdx.x];
  if (i < N_NODES) row_ptr[i] = incl - v;
  if (i == N_NODES - 1) row_ptr[N_NODES] = incl;
}

__global__ void k_fill(const int* __restrict__ src, const int* __restrict__ dst,
                       const int* __restrict__ row_ptr, int* __restrict__ cursor,
                       int* __restrict__ col) {
  int e = blockIdx.x * blockDim.x + threadIdx.x;
  if (e < N_EDGES) {
    int d = dst[e];
    int pos = row_ptr[d] + atomicAdd(&cursor[d], 1);
    col[pos] = src[e];
  }
}

__global__ void k_dinv(const int* __restrict__ deg, float* __restrict__ dinv) {
  int i = blockIdx.x * blockDim.x + threadIdx.x;
  if (i < N_NODES) dinv[i] = rsqrtf((float)(deg[i] + 1));
}

// ---------------- node-feature GEMM: Y[M,NN] = X[M,KK] @ W[KK,NN] ----------------
// block: 64 rows x NN cols, 256 threads, thread tile 4 rows x (CG groups of 4 cols)

template<int NN, int KK>
__global__ __launch_bounds__(256) void node_gemm(
    const float* __restrict__ X, const float* __restrict__ W,
    float* __restrict__ Y) {
  constexpr int KT = 32;
  constexpr int CG = NN / 64;     // 2 for NN=128, 1 for NN=64
  __shared__ float xs[64][KT + 1];
  __shared__ float ws_[KT][NN];
  int t = threadIdx.x, tx = t & 15, ty = t >> 4;
  int m0 = blockIdx.x * 64;
  float acc[4][CG][4] = {};

  for (int kk = 0; kk < KK; kk += KT) {
    __syncthreads();
    // stage X tile (64 x 32), zero-fill rows beyond M
#pragma unroll
    for (int j = 0; j < 8; ++j) {
      int r = (t >> 5) + j * 8, c = t & 31;
      int m = m0 + r;
      xs[r][c] = (m < N_NODES) ? X[(size_t)m * KK + kk + c] : 0.f;
    }
    // stage W tile (32 x NN)
#pragma unroll
    for (int j = 0; j < KT * NN / 256; ++j) {
      int idx = t + j * 256;
      int r = idx / NN, c = idx % NN;
      ws_[r][c] = W[(size_t)(kk + r) * NN + c];
    }
    __syncthreads();
#pragma unroll
    for (int k = 0; k < KT; ++k) {
      float xv[4];
#pragma unroll
      for (int r = 0; r < 4; ++r) xv[r] = xs[ty * 4 + r][k];
#pragma unroll
      for (int g = 0; g < CG; ++g) {
        float4 wv = *(const float4*)&ws_[k][g * 64 + tx * 4];
#pragma unroll
        for (int r = 0; r < 4; ++r) {
          acc[r][g][0] += xv[r] * wv.x;
          acc[r][g][1] += xv[r] * wv.y;
          acc[r][g][2] += xv[r] * wv.z;
          acc[r][g][3] += xv[r] * wv.w;
        }
      }
    }
  }
#pragma unroll
  for (int r = 0; r < 4; ++r) {
    int m = m0 + ty * 4 + r;
    if (m < N_NODES) {
#pragma unroll
      for (int g = 0; g < CG; ++g) {
        float4 v = make_float4(acc[r][g][0], acc[r][g][1], acc[r][g][2], acc[r][g][3]);
        *(float4*)&Y[(size_t)m * NN + g * 64 + tx * 4] = v;
      }
    }
  }
}

// ---------------- aggregation: out[i] = bias + dinv[i]*(dinv[i]*A[i] + sum dinv[s]*A[s]) ----

template<int NF, bool RELU>
__global__ void k_agg(const float* __restrict__ Ain, const float* __restrict__ dinv,
                      const int* __restrict__ row_ptr, const int* __restrict__ col,
                      const float* __restrict__ bias, float* __restrict__ out) {
  int i = blockIdx.x;
  int f = threadIdx.x;
  float di = dinv[i];
  int beg = row_ptr[i], end = row_ptr[i + 1];
  float acc = di * Ain[(size_t)i * NF + f];
  for (int r = beg; r < end; ++r) {
    int s = col[r];
    acc += dinv[s] * Ain[(size_t)s * NF + f];
  }
  float v = bias[f] + di * acc;
  if (RELU) v = fmaxf(v, 0.f);
  out[(size_t)i * NF + f] = v;
}

// ---------------- final: out[1024,64] += data[1024,50000] @ h2[50000,64] (K-split) ----

__global__ __launch_bounds__(256) void final_mm(
    const float* __restrict__ data, const float* __restrict__ h2,
    float* __restrict__ out, int kc_len) {
  constexpr int KT = 32;
  __shared__ float ds[64][KT + 1];
  __shared__ float hs[KT][FEAT];
  int t = threadIdx.x, tx = t & 15, ty = t >> 4;
  int m0 = blockIdx.x * 64;
  int k0 = blockIdx.y * kc_len;
  int k1 = k0 + kc_len; if (k1 > N_NODES) k1 = N_NODES;
  float acc[4][4] = {};

  for (int kk = k0; kk < k1; kk += KT) {
    int klen = k1 - kk; if (klen > KT) klen = KT;
    __syncthreads();
#pragma unroll
    for (int j = 0; j < 8; ++j) {
      int r = (t >> 5) + j * 8, c = t & 31;
      ds[r][c] = (c < klen) ? data[(size_t)(m0 + r) * N_NODES + kk + c] : 0.f;
    }
#pragma unroll
    for (int j = 0; j < KT * FEAT / 256; ++j) {
      int idx = t + j * 256;
      int r = idx >> 6, c = idx & 63;
      hs[r][c] = (r < klen) ? h2[(size_t)(kk + r) * FEAT + c] : 0.f;
    }
    __syncthreads();
#pragma unroll
    for (int k = 0; k < KT; ++k) {
      float4 hv = *(const float4*)&hs[k][tx * 4];
      float d0 = ds[ty * 4 + 0][k];
      float d1 = ds[ty * 4 + 1][k];
      float d2 = ds[ty * 4 + 2][k];
      float d3 = ds[ty * 4 + 3][k];
      acc[0][0] += d0 * hv.x; acc[0][1] += d0 * hv.y; acc[0][2] += d0 * hv.z; acc[0][3] += d0 * hv.w;
      acc[1][0] += d1 * hv.x; acc[1][1] += d1 * hv.y; acc[1][2] += d1 * hv.z; acc[1][3] += d1 * hv.w;
      acc[2][0] += d2 * hv.x; acc[2][1] += d2 * hv.y; acc[2][2] += d2 * hv.z; acc[2][3] += d2 * hv.w;
      acc[3][0] += d3 * hv.x; acc[3][1] += d3 * hv.y; acc[3][2] += d3 * hv.z; acc[3][3] += d3 * hv.w;
    }
  }
#pragma unroll
  for (int r = 0; r < 4; ++r)
#pragma unroll
    for (int c = 0; c < 4; ++c)
      atomicAdd(&out[(size_t)(m0 + ty * 4 + r) * FEAT + tx * 4 + c], acc[r][c]);
}

// ---------------- launch ----------------

extern "C" void kernel_launch(void* const* d_in, const int* in_sizes, int n_in,
                              void* d_out, int out_size, void* d_ws, size_t ws_size,
                              hipStream_t stream) {
  const float* data = (const float*)d_in[0];
  const float* x    = (const float*)d_in[1];
  const int*   ei   = (const int*)d_in[2];   // [2, E] int32 per harness contract
  const float* W1   = (const float*)d_in[3];
  const float* b1   = (const float*)d_in[4];
  const float* W2   = (const float*)d_in[5];
  const float* b2   = (const float*)d_in[6];
  float* out = (float*)d_out;

  // workspace layout (bytes) — ~55.2 MB total
  char* ws = (char*)d_ws;
  float* A     = (float*)(ws + 0);          // 50000x128 = 25.6 MB (xW, then hW)
  float* Bbuf  = (float*)(ws + 25600000);   // 50000x128 = 25.6 MB (h1, then h2 50000x64)
  int*   deg   = (int*)(ws + 51200000);     // 50000
  int*   rowp  = (int*)(ws + 51400000);     // 50001
  int*   cur   = (int*)(ws + 51600016);     // 50000
  int*   bsum  = (int*)(ws + 51800016);     // 98
  float* dinv  = (float*)(ws + 51800416);   // 50000
  int*   col   = (int*)(ws + 52000416);     // 800000

  const int* srcp = ei;
  const int* dstp = ei + N_EDGES;

  hipMemsetAsync(deg, 0, N_NODES * 4, stream);
  hipMemsetAsync(cur, 0, N_NODES * 4, stream);
  hipMemsetAsync(d_out, 0, (size_t)out_size * 4, stream);

  k_deg<<<(N_EDGES + 255) / 256, 256, 0, stream>>>(dstp, deg);
  int nb = (N_NODES + 511) / 512;  // 98
  k_scan1<<<nb, 512, 0, stream>>>(deg, bsum);
  k_scan2<<<1, 64, 0, stream>>>(bsum, nb);
  k_scan3<<<nb, 512, 0, stream>>>(deg, bsum, rowp);
  k_dinv<<<(N_NODES + 255) / 256, 256, 0, stream>>>(deg, dinv);
  k_fill<<<(N_EDGES + 255) / 256, 256, 0, stream>>>(srcp, dstp, rowp, cur, col);

  // layer 1: xW = x @ W1 ; h1 = relu(agg(xW) + b1)
  node_gemm<HID, GENE><<<(N_NODES + 63) / 64, 256, 0, stream>>>(x, W1, A);
  k_agg<HID, true><<<N_NODES, HID, 0, stream>>>(A, dinv, rowp, col, b1, Bbuf);

  // layer 2: hW = h1 @ W2 ; h2 = agg(hW) + b2
  node_gemm<FEAT, HID><<<(N_NODES + 63) / 64, 256, 0, stream>>>(Bbuf, W2, A);
  k_agg<FEAT, false><<<N_NODES, FEAT, 0, stream>>>(A, dinv, rowp, col, b2, Bbuf);

  // out = data @ h2  (K-split + atomic accumulate; out zeroed above)
  final_mm<<<dim3(16, 98), 256, 0, stream>>>(data, Bbuf, out, 512);
}

// Round 2
// 385.559 us; speedup vs baseline: 1.6294x; 1.6294x over previous
//
#include <hip/hip_runtime.h>
#include <hip/hip_bf16.h>
#include <cstdint>

#define N_NODES 50000
#define N_EDGES 800000
#define GENE    256
#define HID     128
#define FEAT    64

typedef __attribute__((ext_vector_type(8))) short bf16x8;
typedef __attribute__((ext_vector_type(4))) float f32x4;
typedef unsigned short u16;

__device__ __forceinline__ u16 f2b(float f) {
  __hip_bfloat16 h = __float2bfloat16(f);
  return *reinterpret_cast<u16*>(&h);
}
__device__ __forceinline__ float b2f(u16 u) {
  return __uint_as_float(((unsigned)u) << 16);
}

// ---------------- degree / CSR build ----------------

__global__ void k_deg(const int* __restrict__ dst, int* __restrict__ deg) {
  int e = blockIdx.x * blockDim.x + threadIdx.x;
  if (e < N_EDGES) atomicAdd(&deg[dst[e]], 1);
}

__global__ void k_scan1(const int* __restrict__ deg, int* __restrict__ bsum) {
  __shared__ int s[512];
  int t = threadIdx.x;
  int i = blockIdx.x * 512 + t;
  s[t] = (i < N_NODES) ? deg[i] : 0;
  __syncthreads();
  for (int off = 256; off > 0; off >>= 1) {
    if (t < off) s[t] += s[t + off];
    __syncthreads();
  }
  if (t == 0) bsum[blockIdx.x] = s[0];
}

__global__ void k_scan2(int* bsum, int nb) {
  if (threadIdx.x == 0 && blockIdx.x == 0) {
    int acc = 0;
    for (int b = 0; b < nb; ++b) { int v = bsum[b]; bsum[b] = acc; acc += v; }
  }
}

__global__ void k_scan3(const int* __restrict__ deg, const int* __restrict__ bsum,
                        int* __restrict__ row_ptr) {
  __shared__ int s[512];
  int t = threadIdx.x;
  int i = blockIdx.x * 512 + t;
  int v = (i < N_NODES) ? deg[i] : 0;
  s[t] = v;
  __syncthreads();
  for (int off = 1; off < 512; off <<= 1) {
    int add = (t >= off) ? s[t - off] : 0;
    __syncthreads();
    s[t] += add;
    __syncthreads();
  }
  int incl = s[t] + bsum[blockIdx.x];
  if (i < N_NODES) row_ptr[i] = incl - v;
  if (i == N_NODES - 1) row_ptr[N_NODES] = incl;
}

__global__ void k_fill(const int* __restrict__ src, const int* __restrict__ dst,
                       const int* __restrict__ row_ptr, int* __restrict__ cursor,
                       int* __restrict__ col) {
  int e = blockIdx.x * blockDim.x + threadIdx.x;
  if (e < N_EDGES) {
    int d = dst[e];
    int pos = row_ptr[d] + atomicAdd(&cursor[d], 1);
    col[pos] = src[e];
  }
}

__global__ void k_dinv(const int* __restrict__ deg, float* __restrict__ dinv) {
  int i = blockIdx.x * blockDim.x + threadIdx.x;
  if (i < N_NODES) dinv[i] = rsqrtf((float)(deg[i] + 1));
}

// ---------------- W -> Wt bf16 (transposed: Wt[n][k] = W[k][n]) ----------------

template<int NN, int KK>
__global__ void k_wt(const float* __restrict__ W, u16* __restrict__ Wt) {
  int i = blockIdx.x * 256 + threadIdx.x;
  if (i < NN * KK) {
    int n = i / KK, k = i % KK;
    Wt[i] = f2b(W[(size_t)k * NN + n]);
  }
}

// ---------------- MFMA GEMM: Y[M,NN](bf16) = X[M,KK] @ W[KK,NN], Wt[NN][KK] bf16 ----
// 256 threads = 4 waves, each wave: 16 rows x NN cols, full K. No LDS.

template<bool F32IN, int NN, int KK>
__global__ __launch_bounds__(256) void mfma_gemm(const void* __restrict__ Xv,
                                                 const u16* __restrict__ Wt,
                                                 u16* __restrict__ Y) {
  constexpr int NF = NN / 16;
  int t = threadIdx.x;
  int w = t >> 6, l = t & 63;
  int lm = l & 15, lg = l >> 4;
  int m = blockIdx.x * 64 + w * 16 + lm;
  int msafe = (m < N_NODES) ? m : 0;
  f32x4 acc[NF] = {};

#pragma unroll
  for (int k0 = 0; k0 < KK; k0 += 32) {
    bf16x8 a;
    if constexpr (F32IN) {
      const float* xr = (const float*)Xv + (size_t)msafe * KK + k0 + lg * 8;
      float4 f0 = *(const float4*)xr;
      float4 f1 = *(const float4*)(xr + 4);
      a[0] = (short)f2b(f0.x); a[1] = (short)f2b(f0.y);
      a[2] = (short)f2b(f0.z); a[3] = (short)f2b(f0.w);
      a[4] = (short)f2b(f1.x); a[5] = (short)f2b(f1.y);
      a[6] = (short)f2b(f1.z); a[7] = (short)f2b(f1.w);
    } else {
      const u16* xr = (const u16*)Xv + (size_t)msafe * KK + k0 + lg * 8;
      a = *(const bf16x8*)xr;
    }
#pragma unroll
    for (int f = 0; f < NF; ++f) {
      bf16x8 b = *(const bf16x8*)(Wt + (size_t)(f * 16 + lm) * KK + k0 + lg * 8);
      acc[f] = __builtin_amdgcn_mfma_f32_16x16x32_bf16(a, b, acc[f], 0, 0, 0);
    }
  }

  int mo = blockIdx.x * 64 + w * 16 + lg * 4;  // C/D: row=(l>>4)*4+reg, col=l&15
#pragma unroll
  for (int f = 0; f < NF; ++f)
#pragma unroll
    for (int r = 0; r < 4; ++r) {
      int mm = mo + r;
      if (mm < N_NODES) Y[(size_t)mm * NN + f * 16 + lm] = f2b(acc[f][r]);
    }
}

// ---------------- aggregation (bf16 in/out) ----------------

template<int NF, bool RELU>
__global__ void k_agg(const u16* __restrict__ Ain, const float* __restrict__ dinv,
                      const int* __restrict__ row_ptr, const int* __restrict__ col,
                      const float* __restrict__ bias, u16* __restrict__ out) {
  int i = blockIdx.x;
  int f = threadIdx.x;
  float di = dinv[i];
  int beg = row_ptr[i], end = row_ptr[i + 1];
  float acc = di * b2f(Ain[(size_t)i * NF + f]);
  for (int r = beg; r < end; ++r) {
    int s = col[r];
    acc += dinv[s] * b2f(Ain[(size_t)s * NF + f]);
  }
  float v = bias[f] + di * acc;
  if (RELU) v = fmaxf(v, 0.f);
  out[(size_t)i * NF + f] = f2b(v);
}

// ---------------- transpose h2 [N_NODES x 64] -> h2t [64 x N_NODES] ----------------

__global__ __launch_bounds__(256) void k_tr(const u16* __restrict__ h2,
                                            u16* __restrict__ h2t) {
  __shared__ u16 tile[64][65];
  int i0 = blockIdx.x * 64;
  int t = threadIdx.x;
  int r = t >> 2, c0 = (t & 3) * 16;
  int i = i0 + r;
#pragma unroll
  for (int j = 0; j < 16; ++j)
    tile[r][c0 + j] = (i < N_NODES) ? h2[(size_t)i * 64 + c0 + j] : (u16)0;
  __syncthreads();
  int io = t & 63, n0 = (t >> 6) * 16;
  int i2 = i0 + io;
  if (i2 < N_NODES) {
#pragma unroll
    for (int j = 0; j < 16; ++j)
      h2t[(size_t)(n0 + j) * N_NODES + i2] = tile[io][n0 + j];
  }
}

// ---------------- final: out[1024,64] += data[1024,50000] @ h2, K-split MFMA ----------

#define KC 800

__global__ __launch_bounds__(256) void final_mfma(const float* __restrict__ data,
                                                  const u16* __restrict__ h2t,
                                                  float* __restrict__ out) {
  int t = threadIdx.x;
  int w = t >> 6, l = t & 63;
  int lm = l & 15, lg = l >> 4;
  int m = blockIdx.x * 64 + w * 16 + lm;
  int k0 = blockIdx.y * KC;
  int kend = k0 + KC; if (kend > N_NODES) kend = N_NODES;
  f32x4 acc[4] = {};
  const float* drow = data + (size_t)m * N_NODES + lg * 8;

  int k = k0;
#pragma unroll 2
  for (; k + 32 <= kend; k += 32) {
    float4 f0 = *(const float4*)(drow + k);
    float4 f1 = *(const float4*)(drow + k + 4);
    bf16x8 a;
    a[0] = (short)f2b(f0.x); a[1] = (short)f2b(f0.y);
    a[2] = (short)f2b(f0.z); a[3] = (short)f2b(f0.w);
    a[4] = (short)f2b(f1.x); a[5] = (short)f2b(f1.y);
    a[6] = (short)f2b(f1.z); a[7] = (short)f2b(f1.w);
#pragma unroll
    for (int f = 0; f < 4; ++f) {
      bf16x8 b = *(const bf16x8*)(h2t + (size_t)(f * 16 + lm) * N_NODES + k + lg * 8);
      acc[f] = __builtin_amdgcn_mfma_f32_16x16x32_bf16(a, b, acc[f], 0, 0, 0);
    }
  }
  if (k < kend) {  // K tail (kend-k == 16 only on the last chunk)
    bool ok = (k + lg * 8 + 8) <= kend;
    bf16x8 a = {};
    if (ok) {
      float4 f0 = *(const float4*)(drow + k);
      float4 f1 = *(const float4*)(drow + k + 4);
      a[0] = (short)f2b(f0.x); a[1] = (short)f2b(f0.y);
      a[2] = (short)f2b(f0.z); a[3] = (short)f2b(f0.w);
      a[4] = (short)f2b(f1.x); a[5] = (short)f2b(f1.y);
      a[6] = (short)f2b(f1.z); a[7] = (short)f2b(f1.w);
    }
#pragma unroll
    for (int f = 0; f < 4; ++f) {
      bf16x8 b = {};
      if (ok) b = *(const bf16x8*)(h2t + (size_t)(f * 16 + lm) * N_NODES + k + lg * 8);
      acc[f] = __builtin_amdgcn_mfma_f32_16x16x32_bf16(a, b, acc[f], 0, 0, 0);
    }
  }

  int mo = blockIdx.x * 64 + w * 16 + lg * 4;
#pragma unroll
  for (int f = 0; f < 4; ++f)
#pragma unroll
    for (int r = 0; r < 4; ++r)
      atomicAdd(&out[(size_t)(mo + r) * FEAT + f * 16 + lm], acc[f][r]);
}

// ---------------- launch ----------------

extern "C" void kernel_launch(void* const* d_in, const int* in_sizes, int n_in,
                              void* d_out, int out_size, void* d_ws, size_t ws_size,
                              hipStream_t stream) {
  const float* data = (const float*)d_in[0];
  const float* x    = (const float*)d_in[1];
  const int*   ei   = (const int*)d_in[2];
  const float* W1   = (const float*)d_in[3];
  const float* b1   = (const float*)d_in[4];
  const float* W2   = (const float*)d_in[5];
  const float* b2   = (const float*)d_in[6];
  float* out = (float*)d_out;

  char* ws = (char*)d_ws;
  u16*   A    = (u16*)(ws + 0);          // 50000x128 bf16 = 12.8 MB (xW / hW / h2 reuse)
  u16*   Hb   = (u16*)(ws + 12800000);   // 50000x128 bf16 = 12.8 MB (h1 / h2)
  u16*   h2t  = (u16*)(ws + 25600000);   // 64x50000 bf16 = 6.4 MB
  u16*   Wt1  = (u16*)(ws + 32000000);   // 128x256
  u16*   Wt2  = (u16*)(ws + 32065536);   // 64x128
  int*   deg  = (int*)(ws + 32081920);
  int*   rowp = (int*)(ws + 32281920);
  int*   cur  = (int*)(ws + 32481936);
  int*   bsum = (int*)(ws + 32681936);
  float* dinv = (float*)(ws + 32682448);
  int*   col  = (int*)(ws + 32882448);

  const int* srcp = ei;
  const int* dstp = ei + N_EDGES;

  hipMemsetAsync(deg, 0, N_NODES * 4, stream);
  hipMemsetAsync(cur, 0, N_NODES * 4, stream);
  hipMemsetAsync(d_out, 0, (size_t)out_size * 4, stream);

  k_deg<<<(N_EDGES + 255) / 256, 256, 0, stream>>>(dstp, deg);
  int nb = (N_NODES + 511) / 512;
  k_scan1<<<nb, 512, 0, stream>>>(deg, bsum);
  k_scan2<<<1, 64, 0, stream>>>(bsum, nb);
  k_scan3<<<nb, 512, 0, stream>>>(deg, bsum, rowp);
  k_dinv<<<(N_NODES + 255) / 256, 256, 0, stream>>>(deg, dinv);
  k_fill<<<(N_EDGES + 255) / 256, 256, 0, stream>>>(srcp, dstp, rowp, cur, col);

  k_wt<HID, GENE><<<(HID * GENE + 255) / 256, 256, 0, stream>>>(W1, Wt1);
  k_wt<FEAT, HID><<<(FEAT * HID + 255) / 256, 256, 0, stream>>>(W2, Wt2);

  // layer 1
  mfma_gemm<true, HID, GENE><<<(N_NODES + 63) / 64, 256, 0, stream>>>(x, Wt1, A);
  k_agg<HID, true><<<N_NODES, HID, 0, stream>>>(A, dinv, rowp, col, b1, Hb);

  // layer 2
  mfma_gemm<false, FEAT, HID><<<(N_NODES + 63) / 64, 256, 0, stream>>>(Hb, Wt2, A);
  k_agg<FEAT, false><<<N_NODES, FEAT, 0, stream>>>(A, dinv, rowp, col, b2, Hb);

  // transpose h2 -> h2t
  k_tr<<<(N_NODES + 63) / 64, 256, 0, stream>>>(Hb, h2t);

  // final GEMM, K-split 63 chunks of 800
  final_mfma<<<dim3(16, 63), 256, 0, stream>>>(data, h2t, out);
}

// Round 3
// 378.492 us; speedup vs baseline: 1.6598x; 1.0187x over previous
//
#include <hip/hip_runtime.h>
#include <hip/hip_bf16.h>
#include <cstdint>

#define N_NODES 50000
#define N_EDGES 800000
#define GENE    256
#define HID     128
#define FEAT    64

typedef __attribute__((ext_vector_type(8))) short bf16x8;
typedef __attribute__((ext_vector_type(4))) float f32x4;
typedef unsigned short u16;

__device__ __forceinline__ u16 f2b(float f) {
  __hip_bfloat16 h = __float2bfloat16(f);
  return *reinterpret_cast<u16*>(&h);
}
__device__ __forceinline__ float b2f(u16 u) {
  return __uint_as_float(((unsigned)u) << 16);
}

// ---------------- zero-init (replaces hipMemsetAsync graph nodes) ----------------

__global__ void k_zero(int* __restrict__ deg, int* __restrict__ cur,
                       float* __restrict__ out) {
  int i = blockIdx.x * 256 + threadIdx.x;
  if (i < N_NODES) { deg[i] = 0; cur[i] = 0; }
  if (i < 1024 * FEAT) out[i] = 0.f;
}

// ---------------- degree / CSR build ----------------

__global__ void k_deg(const int* __restrict__ dst, int* __restrict__ deg) {
  int e = blockIdx.x * blockDim.x + threadIdx.x;
  if (e < N_EDGES) atomicAdd(&deg[dst[e]], 1);
}

__global__ void k_scan1(const int* __restrict__ deg, int* __restrict__ bsum) {
  __shared__ int s[512];
  int t = threadIdx.x;
  int i = blockIdx.x * 512 + t;
  s[t] = (i < N_NODES) ? deg[i] : 0;
  __syncthreads();
  for (int off = 256; off > 0; off >>= 1) {
    if (t < off) s[t] += s[t + off];
    __syncthreads();
  }
  if (t == 0) bsum[blockIdx.x] = s[0];
}

__global__ void k_scan2(int* bsum, int nb) {
  if (threadIdx.x == 0 && blockIdx.x == 0) {
    int acc = 0;
    for (int b = 0; b < nb; ++b) { int v = bsum[b]; bsum[b] = acc; acc += v; }
  }
}

__global__ void k_scan3(const int* __restrict__ deg, const int* __restrict__ bsum,
                        int* __restrict__ row_ptr) {
  __shared__ int s[512];
  int t = threadIdx.x;
  int i = blockIdx.x * 512 + t;
  int v = (i < N_NODES) ? deg[i] : 0;
  s[t] = v;
  __syncthreads();
  for (int off = 1; off < 512; off <<= 1) {
    int add = (t >= off) ? s[t - off] : 0;
    __syncthreads();
    s[t] += add;
    __syncthreads();
  }
  int incl = s[t] + bsum[blockIdx.x];
  if (i < N_NODES) row_ptr[i] = incl - v;
  if (i == N_NODES - 1) row_ptr[N_NODES] = incl;
}

__global__ void k_fill(const int* __restrict__ src, const int* __restrict__ dst,
                       const int* __restrict__ row_ptr, int* __restrict__ cursor,
                       int* __restrict__ col) {
  int e = blockIdx.x * blockDim.x + threadIdx.x;
  if (e < N_EDGES) {
    int d = dst[e];
    int pos = row_ptr[d] + atomicAdd(&cursor[d], 1);
    col[pos] = src[e];
  }
}

__global__ void k_dinv(const int* __restrict__ deg, float* __restrict__ dinv) {
  int i = blockIdx.x * blockDim.x + threadIdx.x;
  if (i < N_NODES) dinv[i] = rsqrtf((float)(deg[i] + 1));
}

// ---------------- W -> Wt bf16 (transposed: Wt[n][k] = W[k][n]) ----------------

template<int NN, int KK>
__global__ void k_wt(const float* __restrict__ W, u16* __restrict__ Wt) {
  int i = blockIdx.x * 256 + threadIdx.x;
  if (i < NN * KK) {
    int n = i / KK, k = i % KK;
    Wt[i] = f2b(W[(size_t)k * NN + n]);
  }
}

// ---------------- MFMA GEMM: Y[M,NN](bf16) = X[M,KK] @ W[KK,NN], Wt[NN][KK] bf16 ----

template<bool F32IN, int NN, int KK>
__global__ __launch_bounds__(256) void mfma_gemm(const void* __restrict__ Xv,
                                                 const u16* __restrict__ Wt,
                                                 u16* __restrict__ Y) {
  constexpr int NF = NN / 16;
  int t = threadIdx.x;
  int w = t >> 6, l = t & 63;
  int lm = l & 15, lg = l >> 4;
  int m = blockIdx.x * 64 + w * 16 + lm;
  int msafe = (m < N_NODES) ? m : 0;
  f32x4 acc[NF] = {};

#pragma unroll
  for (int k0 = 0; k0 < KK; k0 += 32) {
    bf16x8 a;
    if constexpr (F32IN) {
      const float* xr = (const float*)Xv + (size_t)msafe * KK + k0 + lg * 8;
      float4 f0 = *(const float4*)xr;
      float4 f1 = *(const float4*)(xr + 4);
      a[0] = (short)f2b(f0.x); a[1] = (short)f2b(f0.y);
      a[2] = (short)f2b(f0.z); a[3] = (short)f2b(f0.w);
      a[4] = (short)f2b(f1.x); a[5] = (short)f2b(f1.y);
      a[6] = (short)f2b(f1.z); a[7] = (short)f2b(f1.w);
    } else {
      const u16* xr = (const u16*)Xv + (size_t)msafe * KK + k0 + lg * 8;
      a = *(const bf16x8*)xr;
    }
#pragma unroll
    for (int f = 0; f < NF; ++f) {
      bf16x8 b = *(const bf16x8*)(Wt + (size_t)(f * 16 + lm) * KK + k0 + lg * 8);
      acc[f] = __builtin_amdgcn_mfma_f32_16x16x32_bf16(a, b, acc[f], 0, 0, 0);
    }
  }

  int mo = blockIdx.x * 64 + w * 16 + lg * 4;  // C/D: row=(l>>4)*4+reg, col=l&15
#pragma unroll
  for (int f = 0; f < NF; ++f)
#pragma unroll
    for (int r = 0; r < 4; ++r) {
      int mm = mo + r;
      if (mm < N_NODES) Y[(size_t)mm * NN + f * 16 + lm] = f2b(acc[f][r]);
    }
}

// ---------------- aggregation (bf16 in/out) ----------------

template<int NF, bool RELU>
__global__ void k_agg(const u16* __restrict__ Ain, const float* __restrict__ dinv,
                      const int* __restrict__ row_ptr, const int* __restrict__ col,
                      const float* __restrict__ bias, u16* __restrict__ out) {
  int i = blockIdx.x;
  int f = threadIdx.x;
  float di = dinv[i];
  int beg = row_ptr[i], end = row_ptr[i + 1];
  float acc = di * b2f(Ain[(size_t)i * NF + f]);
  for (int r = beg; r < end; ++r) {
    int s = col[r];
    acc += dinv[s] * b2f(Ain[(size_t)s * NF + f]);
  }
  float v = bias[f] + di * acc;
  if (RELU) v = fmaxf(v, 0.f);
  out[(size_t)i * NF + f] = f2b(v);
}

// ---------------- transpose h2 [N_NODES x 64] -> h2t [64 x N_NODES] ----------------

__global__ __launch_bounds__(256) void k_tr(const u16* __restrict__ h2,
                                            u16* __restrict__ h2t) {
  __shared__ u16 tile[64][65];
  int i0 = blockIdx.x * 64;
  int t = threadIdx.x;
  int r = t >> 2, c0 = (t & 3) * 16;
  int i = i0 + r;
#pragma unroll
  for (int j = 0; j < 16; ++j)
    tile[r][c0 + j] = (i < N_NODES) ? h2[(size_t)i * 64 + c0 + j] : (u16)0;
  __syncthreads();
  int io = t & 63, n0 = (t >> 6) * 16;
  int i2 = i0 + io;
  if (i2 < N_NODES) {
#pragma unroll
    for (int j = 0; j < 16; ++j)
      h2t[(size_t)(n0 + j) * N_NODES + i2] = tile[io][n0 + j];
  }
}

// ---------------- final: out[1024,64] += data[1024,50000] @ h2, K-split MFMA ----------

#define KC 800

__global__ __launch_bounds__(256) void final_mfma(const float* __restrict__ data,
                                                  const u16* __restrict__ h2t,
                                                  float* __restrict__ out) {
  int t = threadIdx.x;
  int w = t >> 6, l = t & 63;
  int lm = l & 15, lg = l >> 4;
  int m = blockIdx.x * 64 + w * 16 + lm;
  int k0 = blockIdx.y * KC;
  int kend = k0 + KC; if (kend > N_NODES) kend = N_NODES;
  f32x4 acc[4] = {};
  const float* drow = data + (size_t)m * N_NODES + lg * 8;

  int k = k0;
#pragma unroll 2
  for (; k + 32 <= kend; k += 32) {
    float4 f0 = *(const float4*)(drow + k);
    float4 f1 = *(const float4*)(drow + k + 4);
    bf16x8 a;
    a[0] = (short)f2b(f0.x); a[1] = (short)f2b(f0.y);
    a[2] = (short)f2b(f0.z); a[3] = (short)f2b(f0.w);
    a[4] = (short)f2b(f1.x); a[5] = (short)f2b(f1.y);
    a[6] = (short)f2b(f1.z); a[7] = (short)f2b(f1.w);
#pragma unroll
    for (int f = 0; f < 4; ++f) {
      bf16x8 b = *(const bf16x8*)(h2t + (size_t)(f * 16 + lm) * N_NODES + k + lg * 8);
      acc[f] = __builtin_amdgcn_mfma_f32_16x16x32_bf16(a, b, acc[f], 0, 0, 0);
    }
  }
  if (k < kend) {  // K tail
    bool ok = (k + lg * 8 + 8) <= kend;
    bf16x8 a = {};
    if (ok) {
      float4 f0 = *(const float4*)(drow + k);
      float4 f1 = *(const float4*)(drow + k + 4);
      a[0] = (short)f2b(f0.x); a[1] = (short)f2b(f0.y);
      a[2] = (short)f2b(f0.z); a[3] = (short)f2b(f0.w);
      a[4] = (short)f2b(f1.x); a[5] = (short)f2b(f1.y);
      a[6] = (short)f2b(f1.z); a[7] = (short)f2b(f1.w);
    }
#pragma unroll
    for (int f = 0; f < 4; ++f) {
      bf16x8 b = {};
      if (ok) b = *(const bf16x8*)(h2t + (size_t)(f * 16 + lm) * N_NODES + k + lg * 8);
      acc[f] = __builtin_amdgcn_mfma_f32_16x16x32_bf16(a, b, acc[f], 0, 0, 0);
    }
  }

  int mo = blockIdx.x * 64 + w * 16 + lg * 4;
#pragma unroll
  for (int f = 0; f < 4; ++f)
#pragma unroll
    for (int r = 0; r < 4; ++r)
      atomicAdd(&out[(size_t)(mo + r) * FEAT + f * 16 + lm], acc[f][r]);
}

// ---------------- launch ----------------

extern "C" void kernel_launch(void* const* d_in, const int* in_sizes, int n_in,
                              void* d_out, int out_size, void* d_ws, size_t ws_size,
                              hipStream_t stream) {
  const float* data = (const float*)d_in[0];
  const float* x    = (const float*)d_in[1];
  const int*   ei   = (const int*)d_in[2];
  const float* W1   = (const float*)d_in[3];
  const float* b1   = (const float*)d_in[4];
  const float* W2   = (const float*)d_in[5];
  const float* b2   = (const float*)d_in[6];
  float* out = (float*)d_out;

  char* ws = (char*)d_ws;
  u16*   A    = (u16*)(ws + 0);          // 50000x128 bf16 = 12.8 MB
  u16*   Hb   = (u16*)(ws + 12800000);   // 50000x128 bf16 = 12.8 MB
  u16*   h2t  = (u16*)(ws + 25600000);   // 64x50000 bf16 = 6.4 MB
  u16*   Wt1  = (u16*)(ws + 32000000);   // 128x256
  u16*   Wt2  = (u16*)(ws + 32065536);   // 64x128
  int*   deg  = (int*)(ws + 32081920);
  int*   rowp = (int*)(ws + 32281920);
  int*   cur  = (int*)(ws + 32481936);
  int*   bsum = (int*)(ws + 32681936);
  float* dinv = (float*)(ws + 32682448);
  int*   col  = (int*)(ws + 32882448);

  const int* srcp = ei;
  const int* dstp = ei + N_EDGES;

  // zero deg/cur/out on the compute stream (hipMemsetAsync graph nodes cost ~117us each)
  k_zero<<<256, 256, 0, stream>>>(deg, cur, out);

  k_deg<<<(N_EDGES + 255) / 256, 256, 0, stream>>>(dstp, deg);
  int nb = (N_NODES + 511) / 512;
  k_scan1<<<nb, 512, 0, stream>>>(deg, bsum);
  k_scan2<<<1, 64, 0, stream>>>(bsum, nb);
  k_scan3<<<nb, 512, 0, stream>>>(deg, bsum, rowp);
  k_dinv<<<(N_NODES + 255) / 256, 256, 0, stream>>>(deg, dinv);
  k_fill<<<(N_EDGES + 255) / 256, 256, 0, stream>>>(srcp, dstp, rowp, cur, col);

  k_wt<HID, GENE><<<(HID * GENE + 255) / 256, 256, 0, stream>>>(W1, Wt1);
  k_wt<FEAT, HID><<<(FEAT * HID + 255) / 256, 256, 0, stream>>>(W2, Wt2);

  // layer 1
  mfma_gemm<true, HID, GENE><<<(N_NODES + 63) / 64, 256, 0, stream>>>(x, Wt1, A);
  k_agg<HID, true><<<N_NODES, HID, 0, stream>>>(A, dinv, rowp, col, b1, Hb);

  // layer 2
  mfma_gemm<false, FEAT, HID><<<(N_NODES + 63) / 64, 256, 0, stream>>>(Hb, Wt2, A);
  k_agg<FEAT, false><<<N_NODES, FEAT, 0, stream>>>(A, dinv, rowp, col, b2, Hb);

  // transpose h2 -> h2t
  k_tr<<<(N_NODES + 63) / 64, 256, 0, stream>>>(Hb, h2t);

  // final GEMM, K-split 63 chunks of 800
  final_mfma<<<dim3(16, 63), 256, 0, stream>>>(data, h2t, out);
}

// Round 4
// 356.772 us; speedup vs baseline: 1.7608x; 1.0609x over previous
//
#include <hip/hip_runtime.h>
#include <hip/hip_bf16.h>
#include <cstdint>

#define N_NODES 50000
#define N_EDGES 800000
#define GENE    256
#define HID     128
#define FEAT    64
#define NCHUNK  63
#define KC      800

typedef __attribute__((ext_vector_type(8))) short bf16x8;
typedef __attribute__((ext_vector_type(4))) float f32x4;
typedef unsigned short u16;

__device__ __forceinline__ u16 f2b(float f) {
  __hip_bfloat16 h = __float2bfloat16(f);
  return *reinterpret_cast<u16*>(&h);
}
__device__ __forceinline__ float b2f(u16 u) {
  return __uint_as_float(((unsigned)u) << 16);
}

// ---------------- prep: zero deg/cur + build Wt1/Wt2 (bf16 transposed) ----------------

__global__ void k_prep(int* __restrict__ deg, int* __restrict__ cur,
                       const float* __restrict__ W1, u16* __restrict__ Wt1,
                       const float* __restrict__ W2, u16* __restrict__ Wt2) {
  int i = blockIdx.x * 256 + threadIdx.x;
  if (i < N_NODES) { deg[i] = 0; cur[i] = 0; }
  int j = i - N_NODES;
  if (j >= 0 && j < HID * GENE) {
    int n = j / GENE, k = j % GENE;
    Wt1[j] = f2b(W1[(size_t)k * HID + n]);
  }
  int j2 = j - HID * GENE;
  if (j2 >= 0 && j2 < FEAT * HID) {
    int n = j2 / HID, k = j2 % HID;
    Wt2[j2] = f2b(W2[(size_t)k * FEAT + n]);
  }
}

// ---------------- degree / CSR build ----------------

__global__ void k_deg(const int* __restrict__ dst, int* __restrict__ deg) {
  int e4 = blockIdx.x * blockDim.x + threadIdx.x;
  if (e4 * 4 < N_EDGES) {
    int4 d = *(const int4*)(dst + e4 * 4);
    atomicAdd(&deg[d.x], 1);
    atomicAdd(&deg[d.y], 1);
    atomicAdd(&deg[d.z], 1);
    atomicAdd(&deg[d.w], 1);
  }
}

__global__ void k_scan1(const int* __restrict__ deg, int* __restrict__ bsum) {
  __shared__ int s[512];
  int t = threadIdx.x;
  int i = blockIdx.x * 512 + t;
  s[t] = (i < N_NODES) ? deg[i] : 0;
  __syncthreads();
  for (int off = 256; off > 0; off >>= 1) {
    if (t < off) s[t] += s[t + off];
    __syncthreads();
  }
  if (t == 0) bsum[blockIdx.x] = s[0];
}

__global__ void k_scan2(int* bsum, int nb) {
  if (threadIdx.x == 0 && blockIdx.x == 0) {
    int acc = 0;
    for (int b = 0; b < nb; ++b) { int v = bsum[b]; bsum[b] = acc; acc += v; }
  }
}

__global__ void k_scan3(const int* __restrict__ deg, const int* __restrict__ bsum,
                        int* __restrict__ row_ptr, float* __restrict__ dinv) {
  __shared__ int s[512];
  int t = threadIdx.x;
  int i = blockIdx.x * 512 + t;
  int v = (i < N_NODES) ? deg[i] : 0;
  s[t] = v;
  __syncthreads();
  for (int off = 1; off < 512; off <<= 1) {
    int add = (t >= off) ? s[t - off] : 0;
    __syncthreads();
    s[t] += add;
    __syncthreads();
  }
  int incl = s[t] + bsum[blockIdx.x];
  if (i < N_NODES) {
    row_ptr[i] = incl - v;
    dinv[i] = rsqrtf((float)(v + 1));
  }
  if (i == N_NODES - 1) row_ptr[N_NODES] = incl;
}

__global__ void k_fill(const int* __restrict__ src, const int* __restrict__ dst,
                       const int* __restrict__ row_ptr, int* __restrict__ cursor,
                       int* __restrict__ col) {
  int e4 = blockIdx.x * blockDim.x + threadIdx.x;
  if (e4 * 4 < N_EDGES) {
    int4 d = *(const int4*)(dst + e4 * 4);
    int4 s = *(const int4*)(src + e4 * 4);
    col[row_ptr[d.x] + atomicAdd(&cursor[d.x], 1)] = s.x;
    col[row_ptr[d.y] + atomicAdd(&cursor[d.y], 1)] = s.y;
    col[row_ptr[d.z] + atomicAdd(&cursor[d.z], 1)] = s.z;
    col[row_ptr[d.w] + atomicAdd(&cursor[d.w], 1)] = s.w;
  }
}

// ---- MFMA GEMM: Y[m] = dinv[m] * (X[m] @ W), bf16 out. Wt[n][k] bf16. ----

template<bool F32IN, int NN, int KK>
__global__ __launch_bounds__(256) void mfma_gemm(const void* __restrict__ Xv,
                                                 const u16* __restrict__ Wt,
                                                 const float* __restrict__ dinv,
                                                 u16* __restrict__ Y) {
  constexpr int NF = NN / 16;
  int t = threadIdx.x;
  int w = t >> 6, l = t & 63;
  int lm = l & 15, lg = l >> 4;
  int m = blockIdx.x * 64 + w * 16 + lm;
  int msafe = (m < N_NODES) ? m : 0;
  f32x4 acc[NF] = {};

#pragma unroll
  for (int k0 = 0; k0 < KK; k0 += 32) {
    bf16x8 a;
    if constexpr (F32IN) {
      const float* xr = (const float*)Xv + (size_t)msafe * KK + k0 + lg * 8;
      float4 f0 = *(const float4*)xr;
      float4 f1 = *(const float4*)(xr + 4);
      a[0] = (short)f2b(f0.x); a[1] = (short)f2b(f0.y);
      a[2] = (short)f2b(f0.z); a[3] = (short)f2b(f0.w);
      a[4] = (short)f2b(f1.x); a[5] = (short)f2b(f1.y);
      a[6] = (short)f2b(f1.z); a[7] = (short)f2b(f1.w);
    } else {
      const u16* xr = (const u16*)Xv + (size_t)msafe * KK + k0 + lg * 8;
      a = *(const bf16x8*)xr;
    }
#pragma unroll
    for (int f = 0; f < NF; ++f) {
      bf16x8 b = *(const bf16x8*)(Wt + (size_t)(f * 16 + lm) * KK + k0 + lg * 8);
      acc[f] = __builtin_amdgcn_mfma_f32_16x16x32_bf16(a, b, acc[f], 0, 0, 0);
    }
  }

  int mo = blockIdx.x * 64 + w * 16 + lg * 4;  // C/D: row=(l>>4)*4+r, col=l&15
  float dv[4];
#pragma unroll
  for (int r = 0; r < 4; ++r) dv[r] = (mo + r < N_NODES) ? dinv[mo + r] : 0.f;
#pragma unroll
  for (int f = 0; f < NF; ++f)
#pragma unroll
    for (int r = 0; r < 4; ++r) {
      int mm = mo + r;
      if (mm < N_NODES) Y[(size_t)mm * NN + f * 16 + lm] = f2b(acc[f][r] * dv[r]);
    }
}

// ---- aggregation: out[i] = relu?(bias + dinv[i] * (A'[i] + sum_{s in N(i)} A'[s])) ----
// A' rows are pre-scaled by dinv. 256 threads = (256/NF) nodes per block.

template<int NF, bool RELU>
__global__ __launch_bounds__(256) void k_agg(
    const u16* __restrict__ Ain, const float* __restrict__ dinv,
    const int* __restrict__ row_ptr, const int* __restrict__ col,
    const float* __restrict__ bias, u16* __restrict__ out) {
  constexpr int NPB = 256 / NF;
  int t = threadIdx.x;
  int node = blockIdx.x * NPB + t / NF;
  int f = t % NF;
  float di = dinv[node];
  int beg = row_ptr[node], end = row_ptr[node + 1];
  float acc = b2f(Ain[(size_t)node * NF + f]);  // self (pre-scaled)
  int r = beg;
  for (; r + 4 <= end; r += 4) {
    int s0 = col[r], s1 = col[r + 1], s2 = col[r + 2], s3 = col[r + 3];
    float a0 = b2f(Ain[(size_t)s0 * NF + f]);
    float a1 = b2f(Ain[(size_t)s1 * NF + f]);
    float a2 = b2f(Ain[(size_t)s2 * NF + f]);
    float a3 = b2f(Ain[(size_t)s3 * NF + f]);
    acc += (a0 + a1) + (a2 + a3);
  }
  for (; r < end; ++r) acc += b2f(Ain[(size_t)col[r] * NF + f]);
  float v = bias[f] + di * acc;
  if (RELU) v = fmaxf(v, 0.f);
  out[(size_t)node * NF + f] = f2b(v);
}

// ---------------- transpose h2 [N_NODES x 64] -> h2t [64 x N_NODES] ----------------

__global__ __launch_bounds__(256) void k_tr(const u16* __restrict__ h2,
                                            u16* __restrict__ h2t) {
  __shared__ u16 tile[64][65];
  int i0 = blockIdx.x * 64;
  int t = threadIdx.x;
  int r = t >> 2, c0 = (t & 3) * 16;
  int i = i0 + r;
#pragma unroll
  for (int j = 0; j < 16; ++j)
    tile[r][c0 + j] = (i < N_NODES) ? h2[(size_t)i * 64 + c0 + j] : (u16)0;
  __syncthreads();
  int io = t & 63, n0 = (t >> 6) * 16;
  int i2 = i0 + io;
  if (i2 < N_NODES) {
#pragma unroll
    for (int j = 0; j < 16; ++j)
      h2t[(size_t)(n0 + j) * N_NODES + i2] = tile[io][n0 + j];
  }
}

// ---- final: partial[kc] = data[:, chunk] @ h2[chunk, :]  (no atomics) ----

__global__ __launch_bounds__(256) void final_mfma(const float* __restrict__ data,
                                                  const u16* __restrict__ h2t,
                                                  float* __restrict__ partial) {
  int t = threadIdx.x;
  int w = t >> 6, l = t & 63;
  int lm = l & 15, lg = l >> 4;
  int m = blockIdx.x * 64 + w * 16 + lm;
  int k0 = blockIdx.y * KC;
  int kend = k0 + KC; if (kend > N_NODES) kend = N_NODES;
  f32x4 acc[4] = {};
  const float* drow = data + (size_t)m * N_NODES + lg * 8;

  int k = k0;
#pragma unroll 2
  for (; k + 32 <= kend; k += 32) {
    float4 f0 = *(const float4*)(drow + k);
    float4 f1 = *(const float4*)(drow + k + 4);
    bf16x8 a;
    a[0] = (short)f2b(f0.x); a[1] = (short)f2b(f0.y);
    a[2] = (short)f2b(f0.z); a[3] = (short)f2b(f0.w);
    a[4] = (short)f2b(f1.x); a[5] = (short)f2b(f1.y);
    a[6] = (short)f2b(f1.z); a[7] = (short)f2b(f1.w);
#pragma unroll
    for (int f = 0; f < 4; ++f) {
      bf16x8 b = *(const bf16x8*)(h2t + (size_t)(f * 16 + lm) * N_NODES + k + lg * 8);
      acc[f] = __builtin_amdgcn_mfma_f32_16x16x32_bf16(a, b, acc[f], 0, 0, 0);
    }
  }
  if (k < kend) {  // K tail (16 only)
    bool ok = (k + lg * 8 + 8) <= kend;
    bf16x8 a = {};
    if (ok) {
      float4 f0 = *(const float4*)(drow + k);
      float4 f1 = *(const float4*)(drow + k + 4);
      a[0] = (short)f2b(f0.x); a[1] = (short)f2b(f0.y);
      a[2] = (short)f2b(f0.z); a[3] = (short)f2b(f0.w);
      a[4] = (short)f2b(f1.x); a[5] = (short)f2b(f1.y);
      a[6] = (short)f2b(f1.z); a[7] = (short)f2b(f1.w);
    }
#pragma unroll
    for (int f = 0; f < 4; ++f) {
      bf16x8 b = {};
      if (ok) b = *(const bf16x8*)(h2t + (size_t)(f * 16 + lm) * N_NODES + k + lg * 8);
      acc[f] = __builtin_amdgcn_mfma_f32_16x16x32_bf16(a, b, acc[f], 0, 0, 0);
    }
  }

  float* pout = partial + (size_t)blockIdx.y * (1024 * FEAT);
  int mo = blockIdx.x * 64 + w * 16 + lg * 4;
#pragma unroll
  for (int f = 0; f < 4; ++f)
#pragma unroll
    for (int r = 0; r < 4; ++r)
      pout[(size_t)(mo + r) * FEAT + f * 16 + lm] = acc[f][r];
}

__global__ __launch_bounds__(256) void k_red(const float* __restrict__ partial,
                                             float* __restrict__ out) {
  int i = blockIdx.x * 256 + threadIdx.x;  // 65536 outputs
  float s = 0.f;
#pragma unroll
  for (int c = 0; c < NCHUNK; ++c) s += partial[(size_t)c * (1024 * FEAT) + i];
  out[i] = s;
}

// ---------------- launch ----------------

extern "C" void kernel_launch(void* const* d_in, const int* in_sizes, int n_in,
                              void* d_out, int out_size, void* d_ws, size_t ws_size,
                              hipStream_t stream) {
  const float* data = (const float*)d_in[0];
  const float* x    = (const float*)d_in[1];
  const int*   ei   = (const int*)d_in[2];
  const float* W1   = (const float*)d_in[3];
  const float* b1   = (const float*)d_in[4];
  const float* W2   = (const float*)d_in[5];
  const float* b2   = (const float*)d_in[6];
  float* out = (float*)d_out;

  char* ws = (char*)d_ws;
  u16*   A    = (u16*)(ws + 0);            // 50000x128 bf16
  u16*   Hb   = (u16*)(ws + 12800000);     // 50000x128 bf16
  u16*   h2t  = (u16*)(ws + 25600000);     // 64x50000 bf16
  float* part = (float*)(ws + 32000000);   // 63x1024x64 f32 = 16.5 MB
  u16*   Wt1  = (u16*)(ws + 48515072);     // 128x256 bf16
  u16*   Wt2  = (u16*)(ws + 48580608);     // 64x128 bf16
  int*   deg  = (int*)(ws + 48596992);
  int*   rowp = (int*)(ws + 48796992);
  int*   cur  = (int*)(ws + 48997008);
  int*   bsum = (int*)(ws + 49197008);
  float* dinv = (float*)(ws + 49197520);
  int*   col  = (int*)(ws + 49397520);

  const int* srcp = ei;
  const int* dstp = ei + N_EDGES;

  k_prep<<<(N_NODES + HID * GENE + FEAT * HID + 255) / 256, 256, 0, stream>>>(
      deg, cur, W1, Wt1, W2, Wt2);
  k_deg<<<(N_EDGES / 4 + 255) / 256, 256, 0, stream>>>(dstp, deg);
  int nb = (N_NODES + 511) / 512;
  k_scan1<<<nb, 512, 0, stream>>>(deg, bsum);
  k_scan2<<<1, 64, 0, stream>>>(bsum, nb);
  k_scan3<<<nb, 512, 0, stream>>>(deg, bsum, rowp, dinv);
  k_fill<<<(N_EDGES / 4 + 255) / 256, 256, 0, stream>>>(srcp, dstp, rowp, cur, col);

  // layer 1: A = dinv * (x @ W1); h1 = relu(b1 + dinv*(A_self + sum A_nbr))
  mfma_gemm<true, HID, GENE><<<(N_NODES + 63) / 64, 256, 0, stream>>>(x, Wt1, dinv, A);
  k_agg<HID, true><<<N_NODES / 2, 256, 0, stream>>>(A, dinv, rowp, col, b1, Hb);

  // layer 2
  mfma_gemm<false, FEAT, HID><<<(N_NODES + 63) / 64, 256, 0, stream>>>(Hb, Wt2, dinv, A);
  k_agg<FEAT, false><<<N_NODES / 4, 256, 0, stream>>>(A, dinv, rowp, col, b2, Hb);

  // transpose h2 -> h2t
  k_tr<<<(N_NODES + 63) / 64, 256, 0, stream>>>(Hb, h2t);

  // final GEMM: partials then reduce
  final_mfma<<<dim3(16, NCHUNK), 256, 0, stream>>>(data, h2t, part);
  k_red<<<(1024 * FEAT) / 256, 256, 0, stream>>>(part, out);
}